// Round 5
// baseline (34.312 us; speedup 1.0000x reference)
//
#include <hip/hip_runtime.h>
#include <hip/hip_bf16.h>

#define D_MODEL 256
#define D_K 128
#define MAXM 32     // in-register fast path cap (2 row-tiles of 16)
#define CH 48       // slow-path staging chunk rows

typedef short bf16x8 __attribute__((ext_vector_type(8)));
typedef float f32x4 __attribute__((ext_vector_type(4)));

__device__ inline unsigned short f2bf(float x) {
    union { float f; unsigned u; } v; v.f = x;
    unsigned r = v.u + 0x7FFFu + ((v.u >> 16) & 1u);  // RNE (finite inputs)
    return (unsigned short)(r >> 16);
}
__device__ inline float bf2f(unsigned short h) {
    union { unsigned u; float f; } v; v.u = ((unsigned)h) << 16; return v.f;
}

// ---- LDS layout (27,136 B total) ----
// fast path: Qb [0,8704) Kb [8704,17408) Vb [17408,26112)  (32x136 bf16 each)
//            pmax [26112,26368) psum [26368,26624) csP [26624,26880) csW [26880,27136)
// slow path: At  [0,24576) (48x256 bf16, XOR-swizzled)  emb [26112,26624)
#define AT_BYTE(r, c2) (((r) << 9) + ((((c2) << 1)) ^ (((r) & 7) << 4)))

// ---------------- prep: W pack/transpose + bias + segment boundary scan ----------------
__global__ __launch_bounds__(256) void prep(
    const float* __restrict__ Wq, const float* __restrict__ bq,
    const float* __restrict__ Wk, const float* __restrict__ bk,
    const float* __restrict__ Wv, const float* __restrict__ bv,
    const int* __restrict__ midx,
    unsigned short* __restrict__ Wt, float* __restrict__ Bias, int* __restrict__ Seg,
    int n, int nmol)
{
    const int tid = threadIdx.x, blk = blockIdx.x;
    const float qs = 0.08838834764831845f; // 1/sqrt(128)
    if (blk < 96) {
        // 3*256*128 elems; Wt layout: [which*128 + col][k]
        int e = blk * 1024 + tid * 4;
        int which = e >> 15, rem = e & 32767;
        int r = rem >> 7, c = rem & 127;
        const float* W = which == 0 ? Wq : (which == 1 ? Wk : Wv);
        float sc = which == 0 ? qs : 1.f;
        float4 w = *(const float4*)&W[(size_t)r * D_K + c];
        unsigned short* dst = Wt + (size_t)which * D_K * D_MODEL;
        dst[(size_t)(c + 0) * D_MODEL + r] = f2bf(w.x * sc);
        dst[(size_t)(c + 1) * D_MODEL + r] = f2bf(w.y * sc);
        dst[(size_t)(c + 2) * D_MODEL + r] = f2bf(w.z * sc);
        dst[(size_t)(c + 3) * D_MODEL + r] = f2bf(w.w * sc);
    } else if (blk == 96) {
        for (int t = tid; t < 3 * D_K; t += 256) {
            int which = t >> 7, c = t & 127;
            const float* b = which == 0 ? bq : (which == 1 ? bk : bv);
            Bias[t] = b[c] * (which == 0 ? qs : 1.f);
        }
    } else {
        // boundary scan over sorted midx (replaces 513 binary searches)
        // int64 detection: sorted int64 high words are 0 -> last int32 slot == 0
        const int stride = (midx[n - 1] == 0) ? 2 : 1;
        const int per = (n + 255) >> 8;
        const int i0 = tid * per;
        const int i1 = min(i0 + per, n);
        if (i0 < n) {
            int prev = (i0 == 0) ? -1 : midx[(size_t)(i0 - 1) * stride];
            for (int i = i0; i < i1; ++i) {
                int v = midx[(size_t)i * stride];
                if (v != prev) {
                    for (int u = prev + 1; u <= v; ++u) Seg[u] = i;
                    prev = v;
                }
            }
            if (i1 == n) {
                for (int u = prev + 1; u <= nmol; ++u) Seg[u] = n;
            }
        }
    }
}

// ---------------- fast path (m <= 32): QKV direct-from-global, in-register softmax ----------------
template<int NRT>
__device__ __forceinline__ void fast_path(
    const float* __restrict__ A, const unsigned short* __restrict__ Wt,
    const float* __restrict__ Bias, float* __restrict__ out,
    unsigned char* lds, int s, int m, int mol)
{
    unsigned short* Qb = (unsigned short*)(lds + 0);
    unsigned short* Kb = (unsigned short*)(lds + 8704);
    unsigned short* Vb = (unsigned short*)(lds + 17408);
    float* pmax = (float*)(lds + 26112);
    float* psum = (float*)(lds + 26368);
    float* csP  = (float*)(lds + 26624);
    float* csW  = (float*)(lds + 26880);

    const int tid = threadIdx.x;
    const int wave = tid >> 6, lane = tid & 63;
    const int lr = lane & 15, g = lane >> 4, lk8 = g * 8;

    // ---- QKV: A fragments straight from global (lane-masked rows), Wt fragments from global ----
    f32x4 acc[6][NRT];
    #pragma unroll
    for (int i = 0; i < 6; ++i)
        #pragma unroll
        for (int j = 0; j < NRT; ++j) acc[i][j] = {0.f, 0.f, 0.f, 0.f};

    #pragma unroll
    for (int k0 = 0; k0 < 8; ++k0) {
        bf16x8 af[NRT];
        #pragma unroll
        for (int rt = 0; rt < NRT; ++rt) {
            int row = rt * 16 + lr;
            float4 a0 = make_float4(0.f, 0.f, 0.f, 0.f);
            float4 a1 = a0;
            if (row < m) {
                const float* ap = A + (size_t)(s + row) * D_MODEL + k0 * 32 + lk8;
                a0 = *(const float4*)ap;
                a1 = *(const float4*)(ap + 4);
            }
            unsigned short t8[8] = {f2bf(a0.x), f2bf(a0.y), f2bf(a0.z), f2bf(a0.w),
                                    f2bf(a1.x), f2bf(a1.y), f2bf(a1.z), f2bf(a1.w)};
            af[rt] = *(const bf16x8*)t8;
        }
        #pragma unroll
        for (int cl = 0; cl < 6; ++cl) {
            int ct = wave + cl * 4;
            bf16x8 wf = *(const bf16x8*)(Wt + (size_t)(ct * 16 + lr) * D_MODEL + k0 * 32 + lk8);
            #pragma unroll
            for (int rt = 0; rt < NRT; ++rt)
                acc[cl][rt] = __builtin_amdgcn_mfma_f32_16x16x32_bf16(af[rt], wf, acc[cl][rt], 0, 0, 0);
        }
    }

    // ---- write Q,K,V (+bias) to LDS bf16 ----
    #pragma unroll
    for (int cl = 0; cl < 6; ++cl) {
        int ct = wave + cl * 4;
        int which = ct >> 3;
        int col = (ct & 7) * 16 + lr;
        float bb = Bias[which * D_K + col];
        unsigned short* dst = which == 0 ? Qb : (which == 1 ? Kb : Vb);
        #pragma unroll
        for (int rt = 0; rt < NRT; ++rt) {
            int rbase = rt * 16 + g * 4;
            #pragma unroll
            for (int r = 0; r < 4; ++r)
                dst[(rbase + r) * 136 + col] = f2bf(acc[cl][rt][r] + bb);
        }
    }
    __syncthreads();

    if constexpr (NRT == 1) {
        // every wave redundantly computes the single 16x16 score tile -> zero extra barriers
        f32x4 sa = {0.f, 0.f, 0.f, 0.f};
        #pragma unroll
        for (int kk = 0; kk < 4; ++kk) {
            bf16x8 qf = *(const bf16x8*)&Qb[lr * 136 + kk * 32 + lk8];
            bf16x8 kf = *(const bf16x8*)&Kb[lr * 136 + kk * 32 + lk8];
            sa = __builtin_amdgcn_mfma_f32_16x16x32_bf16(qf, kf, sa, 0, 0, 0);
        }
        const int j = lr;               // C/D: col = lane&15 = K row j
        float sv[4], mx[4], e[4], sm[4];
        #pragma unroll
        for (int r = 0; r < 4; ++r) { sv[r] = (j < m) ? sa[r] : -3.4e38f; mx[r] = sv[r]; }
        #pragma unroll
        for (int msk = 1; msk < 16; msk <<= 1)
            #pragma unroll
            for (int r = 0; r < 4; ++r) mx[r] = fmaxf(mx[r], __shfl_xor(mx[r], msk));
        #pragma unroll
        for (int r = 0; r < 4; ++r) {
            int i = g * 4 + r;          // C/D: row = (lane>>4)*4 + r = Q row i
            e[r] = (i < m) ? __expf(sv[r] - mx[r]) : 0.f;
            sm[r] = e[r];
        }
        #pragma unroll
        for (int msk = 1; msk < 16; msk <<= 1)
            #pragma unroll
            for (int r = 0; r < 4; ++r) sm[r] += __shfl_xor(sm[r], msk);
        #pragma unroll
        for (int r = 0; r < 4; ++r) {
            int i = g * 4 + r;
            float rinv = (i < m && sm[r] > 0.f) ? 1.f / sm[r] : 0.f;
            e[r] *= rinv;
        }
        float cs = e[0] + e[1] + e[2] + e[3];
        cs += __shfl_xor(cs, 16);
        cs += __shfl_xor(cs, 32);       // colsum_j over all 16 rows, in every lane
        if (g == 0) csW[wave * 16 + j] = cs;
        // same-wave LDS RAW (compiler inserts lgkmcnt wait); no cross-wave dep
        int d = wave * 32 + (lane & 31);
        float emb = 0.f;
        #pragma unroll
        for (int jj = 0; jj < 16; ++jj)
            emb += csW[wave * 16 + jj] * bf2f(Vb[jj * 136 + d]);
        if (lane < 32) out[(size_t)mol * D_K + d] = emb;
    } else {
        // 2x2 score tiles, one per wave; cross-tile row reductions via tiny LDS scratch
        const int ti = wave >> 1, tj = wave & 1;
        f32x4 sa = {0.f, 0.f, 0.f, 0.f};
        #pragma unroll
        for (int kk = 0; kk < 4; ++kk) {
            bf16x8 qf = *(const bf16x8*)&Qb[(ti * 16 + lr) * 136 + kk * 32 + lk8];
            bf16x8 kf = *(const bf16x8*)&Kb[(tj * 16 + lr) * 136 + kk * 32 + lk8];
            sa = __builtin_amdgcn_mfma_f32_16x16x32_bf16(qf, kf, sa, 0, 0, 0);
        }
        const int j = tj * 16 + lr;
        float sv[4], mx[4], e[4], sm[4];
        #pragma unroll
        for (int r = 0; r < 4; ++r) { sv[r] = (j < m) ? sa[r] : -3.4e38f; mx[r] = sv[r]; }
        #pragma unroll
        for (int msk = 1; msk < 16; msk <<= 1)
            #pragma unroll
            for (int r = 0; r < 4; ++r) mx[r] = fmaxf(mx[r], __shfl_xor(mx[r], msk));
        if (lr == 0) {
            #pragma unroll
            for (int r = 0; r < 4; ++r) pmax[tj * 32 + ti * 16 + g * 4 + r] = mx[r];
        }
        __syncthreads();
        #pragma unroll
        for (int r = 0; r < 4; ++r) {
            int row = ti * 16 + g * 4 + r;
            float tm = fmaxf(pmax[row], pmax[32 + row]);
            e[r] = __expf(sv[r] - tm);   // j>=m lanes: sv=-inf -> 0
            sm[r] = e[r];
        }
        #pragma unroll
        for (int msk = 1; msk < 16; msk <<= 1)
            #pragma unroll
            for (int r = 0; r < 4; ++r) sm[r] += __shfl_xor(sm[r], msk);
        if (lr == 0) {
            #pragma unroll
            for (int r = 0; r < 4; ++r) psum[tj * 32 + ti * 16 + g * 4 + r] = sm[r];
        }
        __syncthreads();
        #pragma unroll
        for (int r = 0; r < 4; ++r) {
            int row = ti * 16 + g * 4 + r;
            float ts = psum[row] + psum[32 + row];
            float rinv = (row < m && ts > 0.f) ? 1.f / ts : 0.f;
            e[r] *= rinv;
        }
        float cs = e[0] + e[1] + e[2] + e[3];
        cs += __shfl_xor(cs, 16);
        cs += __shfl_xor(cs, 32);        // colsum_j over this tile's 16 rows
        if (lane < 16) csP[ti * 32 + j] = cs;
        __syncthreads();
        int d = wave * 32 + (lane & 31);
        float emb = 0.f;
        #pragma unroll
        for (int jj = 0; jj < 32; ++jj)
            emb += (csP[jj] + csP[32 + jj]) * bf2f(Vb[jj * 136 + d]);
        if (lane < 32) out[(size_t)mol * D_K + d] = emb;
    }
}

// slow-path QKV tile pass: At(LDS) x Wt(global) -> acc[6][3]
__device__ __forceinline__ void qkv_tiles3(
    const unsigned char* lds, const unsigned short* __restrict__ Wt,
    int wave, int lr, int lk8, f32x4 (&acc)[6][3])
{
    #pragma unroll
    for (int cl = 0; cl < 6; ++cl) {
        const int ct = wave + cl * 4;
        const unsigned short* wrow = Wt + (size_t)(ct * 16 + lr) * D_MODEL + lk8;
        #pragma unroll
        for (int k0 = 0; k0 < 8; ++k0) {
            bf16x8 bf = *(const bf16x8*)(wrow + k0 * 32);
            #pragma unroll
            for (int rt = 0; rt < 3; ++rt) {
                bf16x8 af = *(const bf16x8*)(lds + AT_BYTE(rt * 16 + lr, k0 * 32 + lk8));
                acc[cl][rt] = __builtin_amdgcn_mfma_f32_16x16x32_bf16(af, bf, acc[cl][rt], 0, 0, 0);
            }
        }
    }
}

// ---------------- fused: per-molecule QKV + attention + pooling ----------------
__global__ __launch_bounds__(256, 2) void fused(
    const float* __restrict__ A, const unsigned short* __restrict__ Wt,
    const float* __restrict__ Bias, const int* __restrict__ Seg,
    float* __restrict__ out,
    float* __restrict__ Qw, float* __restrict__ Kw, float* __restrict__ Vw,
    float* __restrict__ ML, int n)
{
    __shared__ __align__(16) unsigned char lds[27136];

    const int tid = threadIdx.x, mol = blockIdx.x;
    const int s = Seg[mol], e = Seg[mol + 1];
    const int m = e - s;

    if (m == 0) {
        if (tid < D_K) out[(size_t)mol * D_K + tid] = 0.f;
        return;
    }
    if (m <= 16) { fast_path<1>(A, Wt, Bias, out, lds, s, m, mol); return; }
    if (m <= 32) { fast_path<2>(A, Wt, Bias, out, lds, s, m, mol); return; }

    // ================= slow fallback (m > 32): chunked QKV to global, then streaming =================
    const int wave = tid >> 6, lane = tid & 63;
    const int lr = lane & 15, lk8 = (lane >> 4) * 8;
    float* emb = (float*)(lds + 26112);

    for (int r0 = 0; r0 < m; r0 += CH) {
        #pragma unroll
        for (int it = 0; it < (CH * 256) / 1024; ++it) {
            int eidx = tid * 4 + it * 1024;
            int r = eidx >> 8, c = eidx & 255;
            float4 a;
            if (r0 + r < m) a = *(const float4*)&A[(size_t)(s + r0 + r) * D_MODEL + c];
            else            a = make_float4(0.f, 0.f, 0.f, 0.f);
            unsigned short o[4] = {f2bf(a.x), f2bf(a.y), f2bf(a.z), f2bf(a.w)};
            *(unsigned long long*)(lds + AT_BYTE(r, c)) = *(const unsigned long long*)o;
        }
        __syncthreads();

        f32x4 acc[6][3];
        #pragma unroll
        for (int i = 0; i < 6; ++i)
            #pragma unroll
            for (int j = 0; j < 3; ++j) acc[i][j] = {0.f, 0.f, 0.f, 0.f};
        qkv_tiles3(lds, Wt, wave, lr, lk8, acc);

        #pragma unroll
        for (int cl = 0; cl < 6; ++cl) {
            int ct = wave + cl * 4;
            int which = ct >> 3;
            int col = (ct & 7) * 16 + lr;
            float bb = Bias[which * D_K + col];
            float* dst = which == 0 ? Qw : (which == 1 ? Kw : Vw);
            #pragma unroll
            for (int rt = 0; rt < 3; ++rt) {
                int rbase = rt * 16 + (lane >> 4) * 4;
                #pragma unroll
                for (int r = 0; r < 4; ++r) {
                    int lrow = rbase + r;
                    if (r0 + lrow < m)
                        dst[(size_t)(s + r0 + lrow) * D_K + col] = acc[cl][rt][r] + bb;
                }
            }
        }
        __syncthreads();
    }

    if (tid < D_K) emb[tid] = 0.f;
    float* Mv = ML;
    float* Lv = ML + n;
    __threadfence();   // make this block's Q/K/V global writes visible past L1
    __syncthreads();

    for (int i = tid; i < m; i += 256) {
        const float4* q = (const float4*)(Qw + (size_t)(s + i) * D_K);
        float mx = -3.4e38f, sum = 0.f;
        for (int j = 0; j < m; ++j) {
            const float4* k = (const float4*)(Kw + (size_t)(s + j) * D_K);
            float sc = 0.f;
            #pragma unroll
            for (int t = 0; t < D_K / 4; ++t) {
                float4 a = q[t], b = k[t];
                sc += a.x * b.x + a.y * b.y + a.z * b.z + a.w * b.w;
            }
            if (sc > mx) { sum = sum * __expf(mx - sc) + 1.f; mx = sc; }
            else         { sum += __expf(sc - mx); }
        }
        Mv[s + i] = mx;
        Lv[s + i] = 1.f / sum;
    }
    __threadfence();
    __syncthreads();

    for (int j = tid; j < m; j += 256) {
        const float4* k = (const float4*)(Kw + (size_t)(s + j) * D_K);
        float cj = 0.f;
        for (int i = 0; i < m; ++i) {
            const float4* q = (const float4*)(Qw + (size_t)(s + i) * D_K);
            float sc = 0.f;
            #pragma unroll
            for (int t = 0; t < D_K / 4; ++t) {
                float4 a = q[t], b = k[t];
                sc += a.x * b.x + a.y * b.y + a.z * b.z + a.w * b.w;
            }
            cj += __expf(sc - Mv[s + i]) * Lv[s + i];
        }
        const float* v = Vw + (size_t)(s + j) * D_K;
        for (int d = 0; d < D_K; ++d) atomicAdd(&emb[d], cj * v[d]);
    }
    __syncthreads();
    if (tid < D_K) out[(size_t)mol * D_K + tid] = emb[tid];
}

extern "C" void kernel_launch(void* const* d_in, const int* in_sizes, int n_in,
                              void* d_out, int out_size, void* d_ws, size_t ws_size,
                              hipStream_t stream) {
    const float* frag = (const float*)d_in[0];
    const int*   midx = (const int*)d_in[1];
    const float* Wq = (const float*)d_in[2];
    const float* bq = (const float*)d_in[3];
    const float* Wk = (const float*)d_in[4];
    const float* bk = (const float*)d_in[5];
    const float* Wv = (const float*)d_in[6];
    const float* bv = (const float*)d_in[7];
    float* out = (float*)d_out;

    const int n = in_sizes[1];          // 8192
    const int nmol = out_size / D_K;    // 512

    float* Qw = (float*)d_ws;
    float* Kw = Qw + (size_t)n * D_K;
    float* Vw = Kw + (size_t)n * D_K;
    float* ML = Vw + (size_t)n * D_K;                    // 2*n floats
    unsigned short* Wt = (unsigned short*)(ML + 2 * (size_t)n);
    float* Bias = (float*)(Wt + 3 * (size_t)D_K * D_MODEL);
    int* Seg = (int*)(Bias + 3 * D_K);

    prep<<<98, 256, 0, stream>>>(Wq, bq, Wk, bk, Wv, bv, midx, Wt, Bias, Seg, n, nmol);
    fused<<<nmol, 256, 0, stream>>>(frag, Wt, Bias, Seg, out, Qw, Kw, Vw, ML, n);
}

// Round 6
// 30.862 us; speedup vs baseline: 1.1118x; 1.1118x over previous
//
#include <hip/hip_runtime.h>
#include <hip/hip_bf16.h>

#define D_MODEL 256
#define D_K 128
#define CH 48       // slow-path staging chunk rows; also max fast-path rows (NRT=3)

typedef short bf16x8 __attribute__((ext_vector_type(8)));
typedef float f32x4 __attribute__((ext_vector_type(4)));

__device__ inline unsigned short f2bf(float x) {
    union { float f; unsigned u; } v; v.f = x;
    unsigned r = v.u + 0x7FFFu + ((v.u >> 16) & 1u);  // RNE (finite inputs)
    return (unsigned short)(r >> 16);
}
__device__ inline float bf2f(unsigned short h) {
    union { unsigned u; float f; } v; v.u = ((unsigned)h) << 16; return v.f;
}

// ---- LDS layout (bytes). Total 57,088 -> 2 blocks/CU ----
// At  [48][256] bf16, XOR-swizzled rows (bits 4-6)     : [0, 24576)
// Vb  [48][136] bf16 (aliases At after QKV barrier)    : [0, 13056)
// Qb  [48][136] bf16                                   : [24576, 37632)
// Kb  [48][136] bf16                                   : [37632, 50688)
// S   [48][52]  bf16                                   : [50688, 55680)
// rinv f32[48]                                         : [55680, 55872)
// csum f32[48]                                         : [55872, 56064)
// emb  f32[2][128]                                     : [56064, 57088)
#define AT_BYTE(r, c2) (((r) << 9) + ((((c2) << 1)) ^ (((r) & 7) << 4)))

// QKV tile pass: At(LDS) x Wt(global) -> acc[6][NRT]
// ct = wave + cl*4 covers 24 col-tiles (Q 0-7, K 8-15, V 16-23), rt covers NRT row-tiles.
template<int NRT>
__device__ __forceinline__ void qkv_tiles(
    const unsigned char* lds, const unsigned short* __restrict__ Wt,
    int wave, int lr, int lk8, f32x4 (&acc)[6][NRT])
{
    #pragma unroll
    for (int cl = 0; cl < 6; ++cl) {
        const int ct = wave + cl * 4;
        const unsigned short* wrow = Wt + (size_t)(ct * 16 + lr) * D_MODEL + lk8;
        #pragma unroll
        for (int k0 = 0; k0 < 8; ++k0) {
            bf16x8 bf = *(const bf16x8*)(wrow + k0 * 32);
            #pragma unroll
            for (int rt = 0; rt < NRT; ++rt) {
                bf16x8 af = *(const bf16x8*)(lds + AT_BYTE(rt * 16 + lr, k0 * 32 + lk8));
                acc[cl][rt] = __builtin_amdgcn_mfma_f32_16x16x32_bf16(af, bf, acc[cl][rt], 0, 0, 0);
            }
        }
    }
}

// ---------------- prep: W pack/transpose + bias + segment boundary scan ----------------
__global__ __launch_bounds__(256) void prep(
    const float* __restrict__ Wq, const float* __restrict__ bq,
    const float* __restrict__ Wk, const float* __restrict__ bk,
    const float* __restrict__ Wv, const float* __restrict__ bv,
    const int* __restrict__ midx,
    unsigned short* __restrict__ Wt, float* __restrict__ Bias, int* __restrict__ Seg,
    int n, int nmol)
{
    const int tid = threadIdx.x, blk = blockIdx.x;
    const float qs = 0.08838834764831845f; // 1/sqrt(128)
    if (blk < 96) {
        // 3*256*128 elems; Wt layout: [which*128 + col][k]
        int e = blk * 1024 + tid * 4;
        int which = e >> 15, rem = e & 32767;
        int r = rem >> 7, c = rem & 127;
        const float* W = which == 0 ? Wq : (which == 1 ? Wk : Wv);
        float sc = which == 0 ? qs : 1.f;
        float4 w = *(const float4*)&W[(size_t)r * D_K + c];
        unsigned short* dst = Wt + (size_t)which * D_K * D_MODEL;
        dst[(size_t)(c + 0) * D_MODEL + r] = f2bf(w.x * sc);
        dst[(size_t)(c + 1) * D_MODEL + r] = f2bf(w.y * sc);
        dst[(size_t)(c + 2) * D_MODEL + r] = f2bf(w.z * sc);
        dst[(size_t)(c + 3) * D_MODEL + r] = f2bf(w.w * sc);
    } else if (blk == 96) {
        for (int t = tid; t < 3 * D_K; t += 256) {
            int which = t >> 7, c = t & 127;
            const float* b = which == 0 ? bq : (which == 1 ? bk : bv);
            Bias[t] = b[c] * (which == 0 ? qs : 1.f);
        }
    } else {
        // boundary scan over sorted midx (one coalesced pass, no dependent-load chains)
        // int64 detection: sorted int64 high words are 0 -> last int32 slot == 0
        const int stride = (midx[n - 1] == 0) ? 2 : 1;
        const int per = (n + 255) >> 8;
        const int i0 = tid * per;
        const int i1 = min(i0 + per, n);
        if (i0 < n) {
            int prev = (i0 == 0) ? -1 : midx[(size_t)(i0 - 1) * stride];
            for (int i = i0; i < i1; ++i) {
                int v = midx[(size_t)i * stride];
                if (v != prev) {
                    for (int u = prev + 1; u <= v; ++u) Seg[u] = i;
                    prev = v;
                }
            }
            if (i1 == n) {
                for (int u = prev + 1; u <= nmol; ++u) Seg[u] = n;
            }
        }
    }
}

// ---------------- fast path (m <= NRT*16): round-4 structure, NRT-templated ----------------
template<int NRT>
__device__ __forceinline__ void fast_path(
    const float* __restrict__ A, const unsigned short* __restrict__ Wt,
    const float* __restrict__ Bias, float* __restrict__ out,
    unsigned char* lds, int s, int m, int mol)
{
    unsigned short* Qb = (unsigned short*)(lds + 24576);
    unsigned short* Kb = (unsigned short*)(lds + 37632);
    unsigned short* Vb = (unsigned short*)(lds);        // aliases At (after barrier)
    unsigned short* S  = (unsigned short*)(lds + 50688);
    float* rinv = (float*)(lds + 55680);
    float* csum = (float*)(lds + 55872);
    float* emb  = (float*)(lds + 56064);

    const int tid = threadIdx.x;
    const int wave = tid >> 6, lane = tid & 63;
    const int lr = lane & 15, g = lane >> 4, lk8 = g * 8;

    // ---- stage A rows -> At bf16 (coalesced, zero-pad to NRT*16 rows) ----
    #pragma unroll
    for (int it = 0; it < NRT * 4; ++it) {   // NRT*16 rows * 256 cols / (256 thr * 4 elems)
        int eidx = tid * 4 + it * 1024;
        int r = eidx >> 8, c = eidx & 255;
        float4 a;
        if (r < m) a = *(const float4*)&A[(size_t)(s + r) * D_MODEL + c];
        else       a = make_float4(0.f, 0.f, 0.f, 0.f);
        unsigned short o[4] = {f2bf(a.x), f2bf(a.y), f2bf(a.z), f2bf(a.w)};
        *(unsigned long long*)(lds + AT_BYTE(r, c)) = *(const unsigned long long*)o;
    }
    __syncthreads();

    // ---- QKV MFMA ----
    f32x4 acc[6][NRT];
    #pragma unroll
    for (int i = 0; i < 6; ++i)
        #pragma unroll
        for (int j = 0; j < NRT; ++j) acc[i][j] = {0.f, 0.f, 0.f, 0.f};
    qkv_tiles<NRT>(lds, Wt, wave, lr, lk8, acc);
    __syncthreads();   // all At reads done; Vb may overwrite

    // ---- write Q,K,V (+bias) to LDS bf16 ----
    #pragma unroll
    for (int cl = 0; cl < 6; ++cl) {
        int ct = wave + cl * 4;
        int which = ct >> 3;
        int col = (ct & 7) * 16 + lr;
        float bb = Bias[which * D_K + col];
        unsigned short* dst = which == 0 ? Qb : (which == 1 ? Kb : Vb);
        #pragma unroll
        for (int rt = 0; rt < NRT; ++rt) {
            int rbase = rt * 16 + g * 4;
            #pragma unroll
            for (int r = 0; r < 4; ++r)
                dst[(rbase + r) * 136 + col] = f2bf(acc[cl][rt][r] + bb);
        }
    }
    __syncthreads();

    // ---- scores via MFMA: S[i][j] = Q_i . K_j (scale folded into Wq) ----
    for (int job = wave; job < NRT * NRT; job += 4) {
        int ti = job / NRT, tj = job % NRT;
        f32x4 sa = {0.f, 0.f, 0.f, 0.f};
        #pragma unroll
        for (int kk = 0; kk < 4; ++kk) {
            bf16x8 qf = *(const bf16x8*)&Qb[(ti * 16 + lr) * 136 + kk * 32 + lk8];
            bf16x8 kf = *(const bf16x8*)&Kb[(tj * 16 + lr) * 136 + kk * 32 + lk8];
            sa = __builtin_amdgcn_mfma_f32_16x16x32_bf16(qf, kf, sa, 0, 0, 0);
        }
        int jcol = tj * 16 + lr, ibase = ti * 16 + g * 4;
        #pragma unroll
        for (int r = 0; r < 4; ++r)
            S[(ibase + r) * 52 + jcol] = f2bf(sa[r]);
    }
    __syncthreads();

    // ---- row softmax: 4 lanes per row ----
    {
        int row = tid >> 2, sub = tid & 3;
        if (row < m) {
            float mx = -3.4e38f;
            for (int j = sub; j < m; j += 4) mx = fmaxf(mx, bf2f(S[row * 52 + j]));
            mx = fmaxf(mx, __shfl_xor(mx, 1));
            mx = fmaxf(mx, __shfl_xor(mx, 2));
            float sum = 0.f;
            for (int j = sub; j < m; j += 4) {
                float ev = __expf(bf2f(S[row * 52 + j]) - mx);
                S[row * 52 + j] = f2bf(ev);
                sum += ev;
            }
            sum += __shfl_xor(sum, 1);
            sum += __shfl_xor(sum, 2);
            if (sub == 0) rinv[row] = 1.f / sum;
        }
    }
    __syncthreads();

    // ---- column sums of normalized weights ----
    {
        int col = tid >> 2, sub = tid & 3;
        if (col < m) {
            float a = 0.f;
            for (int i = sub; i < m; i += 4) a += bf2f(S[i * 52 + col]) * rinv[i];
            a += __shfl_xor(a, 1);
            a += __shfl_xor(a, 2);
            if (sub == 0) csum[col] = a;
        }
    }
    __syncthreads();

    // ---- emb[d] = sum_j csum[j] * V[j][d] ----
    {
        int d = tid & 127, h = tid >> 7;
        float a = 0.f;
        for (int j = h; j < m; j += 2) a += csum[j] * bf2f(Vb[j * 136 + d]);
        emb[h * D_K + d] = a;
        __syncthreads();
        if (tid < D_K) out[(size_t)mol * D_K + tid] = emb[tid] + emb[D_K + tid];
    }
}

// ---------------- fused: per-molecule QKV + attention + pooling ----------------
__global__ __launch_bounds__(256, 2) void fused(
    const float* __restrict__ A, const unsigned short* __restrict__ Wt,
    const float* __restrict__ Bias, const int* __restrict__ Seg,
    float* __restrict__ out,
    float* __restrict__ Qw, float* __restrict__ Kw, float* __restrict__ Vw,
    float* __restrict__ ML, int n)
{
    __shared__ __align__(16) unsigned char lds[57088];

    const int tid = threadIdx.x, mol = blockIdx.x;
    const int s = Seg[mol], e = Seg[mol + 1];
    const int m = e - s;

    if (m == 0) {
        if (tid < D_K) out[(size_t)mol * D_K + tid] = 0.f;
        return;
    }
    if (m <= 16) { fast_path<1>(A, Wt, Bias, out, lds, s, m, mol); return; }
    if (m <= 32) { fast_path<2>(A, Wt, Bias, out, lds, s, m, mol); return; }
    if (m <= 48) { fast_path<3>(A, Wt, Bias, out, lds, s, m, mol); return; }

    // ================= slow fallback (m > 48): chunked QKV to global, then streaming =================
    const int wave = tid >> 6, lane = tid & 63;
    const int lr = lane & 15, lk8 = (lane >> 4) * 8;
    float* emb = (float*)(lds + 56064);

    for (int r0 = 0; r0 < m; r0 += CH) {
        #pragma unroll
        for (int it = 0; it < (CH * 256) / 1024; ++it) {
            int eidx = tid * 4 + it * 1024;
            int r = eidx >> 8, c = eidx & 255;
            float4 a;
            if (r0 + r < m) a = *(const float4*)&A[(size_t)(s + r0 + r) * D_MODEL + c];
            else            a = make_float4(0.f, 0.f, 0.f, 0.f);
            unsigned short o[4] = {f2bf(a.x), f2bf(a.y), f2bf(a.z), f2bf(a.w)};
            *(unsigned long long*)(lds + AT_BYTE(r, c)) = *(const unsigned long long*)o;
        }
        __syncthreads();

        f32x4 acc[6][3];
        #pragma unroll
        for (int i = 0; i < 6; ++i)
            #pragma unroll
            for (int j = 0; j < 3; ++j) acc[i][j] = {0.f, 0.f, 0.f, 0.f};
        qkv_tiles<3>(lds, Wt, wave, lr, lk8, acc);

        #pragma unroll
        for (int cl = 0; cl < 6; ++cl) {
            int ct = wave + cl * 4;
            int which = ct >> 3;
            int col = (ct & 7) * 16 + lr;
            float bb = Bias[which * D_K + col];
            float* dst = which == 0 ? Qw : (which == 1 ? Kw : Vw);
            #pragma unroll
            for (int rt = 0; rt < 3; ++rt) {
                int rbase = rt * 16 + (lane >> 4) * 4;
                #pragma unroll
                for (int r = 0; r < 4; ++r) {
                    int lrow = rbase + r;
                    if (r0 + lrow < m)
                        dst[(size_t)(s + r0 + lrow) * D_K + col] = acc[cl][rt][r] + bb;
                }
            }
        }
        __syncthreads();
    }

    if (tid < D_K) emb[tid] = 0.f;
    float* Mv = ML;
    float* Lv = ML + n;
    __threadfence();   // make this block's Q/K/V global writes visible
    __syncthreads();

    for (int i = tid; i < m; i += 256) {
        const float4* q = (const float4*)(Qw + (size_t)(s + i) * D_K);
        float mx = -3.4e38f, sum = 0.f;
        for (int j = 0; j < m; ++j) {
            const float4* k = (const float4*)(Kw + (size_t)(s + j) * D_K);
            float sc = 0.f;
            #pragma unroll
            for (int t = 0; t < D_K / 4; ++t) {
                float4 a = q[t], b = k[t];
                sc += a.x * b.x + a.y * b.y + a.z * b.z + a.w * b.w;
            }
            if (sc > mx) { sum = sum * __expf(mx - sc) + 1.f; mx = sc; }
            else         { sum += __expf(sc - mx); }
        }
        Mv[s + i] = mx;
        Lv[s + i] = 1.f / sum;
    }
    __threadfence();
    __syncthreads();

    for (int j = tid; j < m; j += 256) {
        const float4* k = (const float4*)(Kw + (size_t)(s + j) * D_K);
        float cj = 0.f;
        for (int i = 0; i < m; ++i) {
            const float4* q = (const float4*)(Qw + (size_t)(s + i) * D_K);
            float sc = 0.f;
            #pragma unroll
            for (int t = 0; t < D_K / 4; ++t) {
                float4 a = q[t], b = k[t];
                sc += a.x * b.x + a.y * b.y + a.z * b.z + a.w * b.w;
            }
            cj += __expf(sc - Mv[s + i]) * Lv[s + i];
        }
        const float* v = Vw + (size_t)(s + j) * D_K;
        for (int d = 0; d < D_K; ++d) atomicAdd(&emb[d], cj * v[d]);
    }
    __syncthreads();
    if (tid < D_K) out[(size_t)mol * D_K + tid] = emb[tid];
}

extern "C" void kernel_launch(void* const* d_in, const int* in_sizes, int n_in,
                              void* d_out, int out_size, void* d_ws, size_t ws_size,
                              hipStream_t stream) {
    const float* frag = (const float*)d_in[0];
    const int*   midx = (const int*)d_in[1];
    const float* Wq = (const float*)d_in[2];
    const float* bq = (const float*)d_in[3];
    const float* Wk = (const float*)d_in[4];
    const float* bk = (const float*)d_in[5];
    const float* Wv = (const float*)d_in[6];
    const float* bv = (const float*)d_in[7];
    float* out = (float*)d_out;

    const int n = in_sizes[1];          // 8192
    const int nmol = out_size / D_K;    // 512

    float* Qw = (float*)d_ws;
    float* Kw = Qw + (size_t)n * D_K;
    float* Vw = Kw + (size_t)n * D_K;
    float* ML = Vw + (size_t)n * D_K;                    // 2*n floats
    unsigned short* Wt = (unsigned short*)(ML + 2 * (size_t)n);
    float* Bias = (float*)(Wt + 3 * (size_t)D_K * D_MODEL);
    int* Seg = (int*)(Bias + 3 * D_K);

    prep<<<98, 256, 0, stream>>>(Wq, bq, Wk, bk, Wv, bv, midx, Wt, Bias, Seg, n, nmol);
    fused<<<nmol, 256, 0, stream>>>(frag, Wt, Bias, Seg, out, Qw, Kw, Vw, ML, n);
}

// Round 7
// 27.412 us; speedup vs baseline: 1.2517x; 1.1259x over previous
//
#include <hip/hip_runtime.h>
#include <hip/hip_bf16.h>

#define D_MODEL 256
#define D_K 128
#define CH 48       // slow-path staging chunk rows; also max fast-path rows (NRT=3)

typedef short bf16x8 __attribute__((ext_vector_type(8)));
typedef float f32x4 __attribute__((ext_vector_type(4)));

__device__ inline unsigned short f2bf(float x) {
    union { float f; unsigned u; } v; v.f = x;
    unsigned r = v.u + 0x7FFFu + ((v.u >> 16) & 1u);  // RNE (finite inputs)
    return (unsigned short)(r >> 16);
}
__device__ inline float bf2f(unsigned short h) {
    union { unsigned u; float f; } v; v.u = ((unsigned)h) << 16; return v.f;
}

// ---- fused LDS layout (bytes). Total 57,088 -> 2 blocks/CU ----
// At  [48][256] bf16, XOR-swizzled rows (bits 4-6)     : [0, 24576)
// Vb  [48][136] bf16 (aliases At after QKV barrier)    : [0, 13056)
// Qb  [48][136] bf16                                   : [24576, 37632)
// Kb  [48][136] bf16                                   : [37632, 50688)
// S   [48][52]  bf16                                   : [50688, 55680)
// rinv f32[48]                                         : [55680, 55872)
// csum f32[48]                                         : [55872, 56064)
// emb  f32[2][128]                                     : [56064, 57088)
#define AT_BYTE(r, c2) (((r) << 9) + ((((c2) << 1)) ^ (((r) & 7) << 4)))

// QKV tile pass: At(LDS) x Wt(global) -> acc[6][NRT]
// ct = wave + cl*4 covers 24 col-tiles (Q 0-7, K 8-15, V 16-23), rt covers NRT row-tiles.
template<int NRT>
__device__ __forceinline__ void qkv_tiles(
    const unsigned char* lds, const unsigned short* __restrict__ Wt,
    int wave, int lr, int lk8, f32x4 (&acc)[6][NRT])
{
    #pragma unroll
    for (int cl = 0; cl < 6; ++cl) {
        const int ct = wave + cl * 4;
        const unsigned short* wrow = Wt + (size_t)(ct * 16 + lr) * D_MODEL + lk8;
        #pragma unroll
        for (int k0 = 0; k0 < 8; ++k0) {
            bf16x8 bf = *(const bf16x8*)(wrow + k0 * 32);
            #pragma unroll
            for (int rt = 0; rt < NRT; ++rt) {
                bf16x8 af = *(const bf16x8*)(lds + AT_BYTE(rt * 16 + lr, k0 * 32 + lk8));
                acc[cl][rt] = __builtin_amdgcn_mfma_f32_16x16x32_bf16(af, bf, acc[cl][rt], 0, 0, 0);
            }
        }
    }
}

// ---------------- prep: W pack (LDS transpose, coalesced 16B stores) + bias + parallel boundary scan ----------------
// grid: blocks 0-11 W-pack (which = blk/4, col-chunk = blk%4), block 12 bias, blocks 13-44 scan.
__global__ __launch_bounds__(256) void prep(
    const float* __restrict__ Wq, const float* __restrict__ bq,
    const float* __restrict__ Wk, const float* __restrict__ bk,
    const float* __restrict__ Wv, const float* __restrict__ bv,
    const int* __restrict__ midx,
    unsigned short* __restrict__ Wt, float* __restrict__ Bias, int* __restrict__ Seg,
    int n, int nmol)
{
    const int tid = threadIdx.x, blk = blockIdx.x;
    const float qs = 0.08838834764831845f; // 1/sqrt(128)
    if (blk < 12) {
        __shared__ float T[32][257];   // padded: conflict-free transpose writes
        const int which = blk >> 2, c0 = (blk & 3) * 32;
        const float* W = which == 0 ? Wq : (which == 1 ? Wk : Wv);
        const float sc = which == 0 ? qs : 1.f;
        #pragma unroll
        for (int it = 0; it < 32; ++it) {
            int e = tid + it * 256;
            int r = e >> 5, c = e & 31;          // coalesced read of W[r][c0+c]
            T[c][r] = W[(size_t)r * D_K + c0 + c];
        }
        __syncthreads();
        // thread -> (col c, k-chunk kc): write 64B contiguous bf16, fully coalesced
        const int c = tid >> 3, kc = (tid & 7) * 32;
        unsigned short* dst = Wt + (size_t)(which * D_K + c0 + c) * D_MODEL + kc;
        #pragma unroll
        for (int t = 0; t < 4; ++t) {
            unsigned short o[8];
            #pragma unroll
            for (int u = 0; u < 8; ++u) o[u] = f2bf(T[c][kc + t * 8 + u] * sc);
            *(uint4*)(dst + t * 8) = *(const uint4*)o;
        }
    } else if (blk == 12) {
        for (int t = tid; t < 3 * D_K; t += 256) {
            int which = t >> 7, c = t & 127;
            const float* b = which == 0 ? bq : (which == 1 ? bk : bv);
            Bias[t] = b[c] * (which == 0 ? qs : 1.f);
        }
    } else {
        // parallel boundary detection on sorted midx: thread gid compares midx[gid] vs midx[gid-1]
        const int gid = (blk - 13) * 256 + tid;
        if (gid < n) {
            // int64 detection: sorted int64 high words are 0 -> last int32 slot == 0
            const int stride = (midx[n - 1] == 0) ? 2 : 1;
            const int v = midx[(size_t)gid * stride];
            const int prev = (gid == 0) ? -1 : midx[(size_t)(gid - 1) * stride];
            for (int u = prev + 1; u <= v; ++u) Seg[u] = gid;   // empty when v == prev
            if (gid == n - 1)
                for (int u = v + 1; u <= nmol; ++u) Seg[u] = n;
        }
    }
}

// ---------------- fast path (m <= NRT*16): round-4 structure, NRT-templated ----------------
template<int NRT>
__device__ __forceinline__ void fast_path(
    const float* __restrict__ A, const unsigned short* __restrict__ Wt,
    const float* __restrict__ Bias, float* __restrict__ out,
    unsigned char* lds, int s, int m, int mol)
{
    unsigned short* Qb = (unsigned short*)(lds + 24576);
    unsigned short* Kb = (unsigned short*)(lds + 37632);
    unsigned short* Vb = (unsigned short*)(lds);        // aliases At (after barrier)
    unsigned short* S  = (unsigned short*)(lds + 50688);
    float* rinv = (float*)(lds + 55680);
    float* csum = (float*)(lds + 55872);
    float* emb  = (float*)(lds + 56064);

    const int tid = threadIdx.x;
    const int wave = tid >> 6, lane = tid & 63;
    const int lr = lane & 15, g = lane >> 4, lk8 = g * 8;

    // ---- stage A rows -> At bf16 (coalesced, zero-pad to NRT*16 rows) ----
    #pragma unroll
    for (int it = 0; it < NRT * 4; ++it) {   // NRT*16 rows * 256 cols / (256 thr * 4 elems)
        int eidx = tid * 4 + it * 1024;
        int r = eidx >> 8, c = eidx & 255;
        float4 a;
        if (r < m) a = *(const float4*)&A[(size_t)(s + r) * D_MODEL + c];
        else       a = make_float4(0.f, 0.f, 0.f, 0.f);
        unsigned short o[4] = {f2bf(a.x), f2bf(a.y), f2bf(a.z), f2bf(a.w)};
        *(unsigned long long*)(lds + AT_BYTE(r, c)) = *(const unsigned long long*)o;
    }
    __syncthreads();

    // ---- QKV MFMA ----
    f32x4 acc[6][NRT];
    #pragma unroll
    for (int i = 0; i < 6; ++i)
        #pragma unroll
        for (int j = 0; j < NRT; ++j) acc[i][j] = {0.f, 0.f, 0.f, 0.f};
    qkv_tiles<NRT>(lds, Wt, wave, lr, lk8, acc);
    __syncthreads();   // all At reads done; Vb may overwrite

    // ---- write Q,K,V (+bias) to LDS bf16 ----
    #pragma unroll
    for (int cl = 0; cl < 6; ++cl) {
        int ct = wave + cl * 4;
        int which = ct >> 3;
        int col = (ct & 7) * 16 + lr;
        float bb = Bias[which * D_K + col];
        unsigned short* dst = which == 0 ? Qb : (which == 1 ? Kb : Vb);
        #pragma unroll
        for (int rt = 0; rt < NRT; ++rt) {
            int rbase = rt * 16 + g * 4;
            #pragma unroll
            for (int r = 0; r < 4; ++r)
                dst[(rbase + r) * 136 + col] = f2bf(acc[cl][rt][r] + bb);
        }
    }
    __syncthreads();

    // ---- scores via MFMA: S[i][j] = Q_i . K_j (scale folded into Wq) ----
    for (int job = wave; job < NRT * NRT; job += 4) {
        int ti = job / NRT, tj = job % NRT;
        f32x4 sa = {0.f, 0.f, 0.f, 0.f};
        #pragma unroll
        for (int kk = 0; kk < 4; ++kk) {
            bf16x8 qf = *(const bf16x8*)&Qb[(ti * 16 + lr) * 136 + kk * 32 + lk8];
            bf16x8 kf = *(const bf16x8*)&Kb[(tj * 16 + lr) * 136 + kk * 32 + lk8];
            sa = __builtin_amdgcn_mfma_f32_16x16x32_bf16(qf, kf, sa, 0, 0, 0);
        }
        int jcol = tj * 16 + lr, ibase = ti * 16 + g * 4;
        #pragma unroll
        for (int r = 0; r < 4; ++r)
            S[(ibase + r) * 52 + jcol] = f2bf(sa[r]);
    }
    __syncthreads();

    // ---- row softmax: 4 lanes per row ----
    {
        int row = tid >> 2, sub = tid & 3;
        if (row < m) {
            float mx = -3.4e38f;
            for (int j = sub; j < m; j += 4) mx = fmaxf(mx, bf2f(S[row * 52 + j]));
            mx = fmaxf(mx, __shfl_xor(mx, 1));
            mx = fmaxf(mx, __shfl_xor(mx, 2));
            float sum = 0.f;
            for (int j = sub; j < m; j += 4) {
                float ev = __expf(bf2f(S[row * 52 + j]) - mx);
                S[row * 52 + j] = f2bf(ev);
                sum += ev;
            }
            sum += __shfl_xor(sum, 1);
            sum += __shfl_xor(sum, 2);
            if (sub == 0) rinv[row] = 1.f / sum;
        }
    }
    __syncthreads();

    // ---- column sums of normalized weights ----
    {
        int col = tid >> 2, sub = tid & 3;
        if (col < m) {
            float a = 0.f;
            for (int i = sub; i < m; i += 4) a += bf2f(S[i * 52 + col]) * rinv[i];
            a += __shfl_xor(a, 1);
            a += __shfl_xor(a, 2);
            if (sub == 0) csum[col] = a;
        }
    }
    __syncthreads();

    // ---- emb[d] = sum_j csum[j] * V[j][d] ----
    {
        int d = tid & 127, h = tid >> 7;
        float a = 0.f;
        for (int j = h; j < m; j += 2) a += csum[j] * bf2f(Vb[j * 136 + d]);
        emb[h * D_K + d] = a;
        __syncthreads();
        if (tid < D_K) out[(size_t)mol * D_K + tid] = emb[tid] + emb[D_K + tid];
    }
}

// ---------------- fused: per-molecule QKV + attention + pooling ----------------
__global__ __launch_bounds__(256, 2) void fused(
    const float* __restrict__ A, const unsigned short* __restrict__ Wt,
    const float* __restrict__ Bias, const int* __restrict__ Seg,
    float* __restrict__ out,
    float* __restrict__ Qw, float* __restrict__ Kw, float* __restrict__ Vw,
    float* __restrict__ ML, int n)
{
    __shared__ __align__(16) unsigned char lds[57088];

    const int tid = threadIdx.x, mol = blockIdx.x;
    const int s = Seg[mol], e = Seg[mol + 1];
    const int m = e - s;

    if (m == 0) {
        if (tid < D_K) out[(size_t)mol * D_K + tid] = 0.f;
        return;
    }
    if (m <= 16) { fast_path<1>(A, Wt, Bias, out, lds, s, m, mol); return; }
    if (m <= 32) { fast_path<2>(A, Wt, Bias, out, lds, s, m, mol); return; }
    if (m <= 48) { fast_path<3>(A, Wt, Bias, out, lds, s, m, mol); return; }

    // ================= slow fallback (m > 48): chunked QKV to global, then streaming =================
    const int wave = tid >> 6, lane = tid & 63;
    const int lr = lane & 15, lk8 = (lane >> 4) * 8;
    float* emb = (float*)(lds + 56064);

    for (int r0 = 0; r0 < m; r0 += CH) {
        #pragma unroll
        for (int it = 0; it < (CH * 256) / 1024; ++it) {
            int eidx = tid * 4 + it * 1024;
            int r = eidx >> 8, c = eidx & 255;
            float4 a;
            if (r0 + r < m) a = *(const float4*)&A[(size_t)(s + r0 + r) * D_MODEL + c];
            else            a = make_float4(0.f, 0.f, 0.f, 0.f);
            unsigned short o[4] = {f2bf(a.x), f2bf(a.y), f2bf(a.z), f2bf(a.w)};
            *(unsigned long long*)(lds + AT_BYTE(r, c)) = *(const unsigned long long*)o;
        }
        __syncthreads();

        f32x4 acc[6][3];
        #pragma unroll
        for (int i = 0; i < 6; ++i)
            #pragma unroll
            for (int j = 0; j < 3; ++j) acc[i][j] = {0.f, 0.f, 0.f, 0.f};
        qkv_tiles<3>(lds, Wt, wave, lr, lk8, acc);

        #pragma unroll
        for (int cl = 0; cl < 6; ++cl) {
            int ct = wave + cl * 4;
            int which = ct >> 3;
            int col = (ct & 7) * 16 + lr;
            float bb = Bias[which * D_K + col];
            float* dst = which == 0 ? Qw : (which == 1 ? Kw : Vw);
            #pragma unroll
            for (int rt = 0; rt < 3; ++rt) {
                int rbase = rt * 16 + (lane >> 4) * 4;
                #pragma unroll
                for (int r = 0; r < 4; ++r) {
                    int lrow = rbase + r;
                    if (r0 + lrow < m)
                        dst[(size_t)(s + r0 + lrow) * D_K + col] = acc[cl][rt][r] + bb;
                }
            }
        }
        __syncthreads();
    }

    if (tid < D_K) emb[tid] = 0.f;
    float* Mv = ML;
    float* Lv = ML + n;
    __threadfence();   // make this block's Q/K/V global writes visible
    __syncthreads();

    for (int i = tid; i < m; i += 256) {
        const float4* q = (const float4*)(Qw + (size_t)(s + i) * D_K);
        float mx = -3.4e38f, sum = 0.f;
        for (int j = 0; j < m; ++j) {
            const float4* k = (const float4*)(Kw + (size_t)(s + j) * D_K);
            float sc = 0.f;
            #pragma unroll
            for (int t = 0; t < D_K / 4; ++t) {
                float4 a = q[t], b = k[t];
                sc += a.x * b.x + a.y * b.y + a.z * b.z + a.w * b.w;
            }
            if (sc > mx) { sum = sum * __expf(mx - sc) + 1.f; mx = sc; }
            else         { sum += __expf(sc - mx); }
        }
        Mv[s + i] = mx;
        Lv[s + i] = 1.f / sum;
    }
    __threadfence();
    __syncthreads();

    for (int j = tid; j < m; j += 256) {
        const float4* k = (const float4*)(Kw + (size_t)(s + j) * D_K);
        float cj = 0.f;
        for (int i = 0; i < m; ++i) {
            const float4* q = (const float4*)(Qw + (size_t)(s + i) * D_K);
            float sc = 0.f;
            #pragma unroll
            for (int t = 0; t < D_K / 4; ++t) {
                float4 a = q[t], b = k[t];
                sc += a.x * b.x + a.y * b.y + a.z * b.z + a.w * b.w;
            }
            cj += __expf(sc - Mv[s + i]) * Lv[s + i];
        }
        const float* v = Vw + (size_t)(s + j) * D_K;
        for (int d = 0; d < D_K; ++d) atomicAdd(&emb[d], cj * v[d]);
    }
    __syncthreads();
    if (tid < D_K) out[(size_t)mol * D_K + tid] = emb[tid];
}

extern "C" void kernel_launch(void* const* d_in, const int* in_sizes, int n_in,
                              void* d_out, int out_size, void* d_ws, size_t ws_size,
                              hipStream_t stream) {
    const float* frag = (const float*)d_in[0];
    const int*   midx = (const int*)d_in[1];
    const float* Wq = (const float*)d_in[2];
    const float* bq = (const float*)d_in[3];
    const float* Wk = (const float*)d_in[4];
    const float* bk = (const float*)d_in[5];
    const float* Wv = (const float*)d_in[6];
    const float* bv = (const float*)d_in[7];
    float* out = (float*)d_out;

    const int n = in_sizes[1];          // 8192
    const int nmol = out_size / D_K;    // 512

    float* Qw = (float*)d_ws;
    float* Kw = Qw + (size_t)n * D_K;
    float* Vw = Kw + (size_t)n * D_K;
    float* ML = Vw + (size_t)n * D_K;                    // 2*n floats
    unsigned short* Wt = (unsigned short*)(ML + 2 * (size_t)n);
    float* Bias = (float*)(Wt + 3 * (size_t)D_K * D_MODEL);
    int* Seg = (int*)(Bias + 3 * D_K);

    const int scanBlocks = (n + 255) / 256;              // 32 for n=8192
    prep<<<13 + scanBlocks, 256, 0, stream>>>(Wq, bq, Wk, bk, Wv, bv, midx, Wt, Bias, Seg, n, nmol);
    fused<<<nmol, 256, 0, stream>>>(frag, Wt, Bias, Seg, out, Qw, Kw, Vw, ML, n);
}